// Round 3
// baseline (542.704 us; speedup 1.0000x reference)
//
#include <hip/hip_runtime.h>

#define B_   32
#define N_   512
#define G_   64
#define T_   16
#define D_   256
#define E_   500000
#define M_   1024
#define S_   (B_ * N_)          // 16384 distinct source rows
#define TD_  (T_ * D_)          // 4096 floats between scope_type rows
#define NEG_ (-10000000000.0f)

// ws layout (bytes)
#define WS_WG      0                      // 2 MiB
#define WS_WT      2097152                // 256 KiB
#define WS_FLAG    2359296                // 4 B
#define WS_HIST    2359552                // 64 KiB (16384 ints)
#define WS_CSUM    2425088                // 256 B (64 ints)
#define WS_COFF    2425344                // 256 B (64 ints)
#define WS_SORTED  4194304                // 8 MB (500000 * int4)

// ---------------------------------------------------------------------------
// kernel 0: classify tree_mask storage (flag) AND zero the sort histogram.
// ---------------------------------------------------------------------------
__global__ __launch_bounds__(256) void detect_and_zero(
    const unsigned char* __restrict__ tm, int* __restrict__ flag,
    int* __restrict__ hist) {
  for (int i = threadIdx.x; i < S_; i += 256) hist[i] = 0;
  __shared__ int sA, sB;
  if (threadIdx.x == 0) { sA = 0; sB = 0; }
  __syncthreads();
  int a = 0, b3 = 0;
  for (int i = threadIdx.x; i < B_ * N_; i += 256) {
    const int r = i & 3;
    const unsigned char v = tm[i];
    if (r == 1) a |= v;
    else if (r == 3) b3 |= v;
  }
  if (a)  atomicOr(&sA, 1);
  if (b3) atomicOr(&sB, 1);
  __syncthreads();
  if (threadIdx.x == 0) flag[0] = sA ? 1 : (sB ? 2 : 0);
}

// ---------------------------------------------------------------------------
// kernel 1a: Wt[f][d] = W[d][f] (32x32 LDS tiles, +1 pad)
// ---------------------------------------------------------------------------
__global__ __launch_bounds__(256) void transpose_w(
    const float* __restrict__ W, float* __restrict__ Wt) {
  __shared__ float tile[32][33];
  const int bi = blockIdx.x >> 3;
  const int bj = blockIdx.x & 7;
  const int tx = threadIdx.x & 31;
  const int ty = threadIdx.x >> 5;
#pragma unroll
  for (int r = 0; r < 4; r++)
    tile[ty + r * 8][tx] = W[(size_t)(bi * 32 + ty + r * 8) * D_ + bj * 32 + tx];
  __syncthreads();
#pragma unroll
  for (int r = 0; r < 4; r++)
    Wt[(size_t)(bj * 32 + ty + r * 8) * D_ + bi * 32 + tx] =
        tile[tx][ty + r * 8];
}

// ---------------------------------------------------------------------------
// kernel 1b: Wg[j][d] = sum_f goal_type[j][f] * Wt[f][d]
// ---------------------------------------------------------------------------
__global__ __launch_bounds__(256) void wg_gemm(
    const float* __restrict__ goal, const float* __restrict__ Wt,
    float* __restrict__ Wg) {
  __shared__ float g[8][256];
  const int j0 = blockIdx.x * 8;
  const int d  = threadIdx.x;
  {
    const int lane = threadIdx.x & 63;
    const int r0   = threadIdx.x >> 6;
#pragma unroll
    for (int rr = 0; rr < 2; rr++) {
      const int row = rr * 4 + r0;
      const float4 v = *reinterpret_cast<const float4*>(
          goal + (size_t)(j0 + row) * TD_ + lane * 4);
      float* dst = &g[row][lane * 4];
      dst[0] = v.x; dst[1] = v.y; dst[2] = v.z; dst[3] = v.w;
    }
  }
  __syncthreads();
  float acc[8];
#pragma unroll
  for (int jj = 0; jj < 8; jj++) acc[jj] = 0.f;
#pragma unroll 4
  for (int f = 0; f < D_; f++) {
    const float w = Wt[(size_t)f * D_ + d];
#pragma unroll
    for (int jj = 0; jj < 8; jj++) acc[jj] = fmaf(g[jj][f], w, acc[jj]);
  }
#pragma unroll
  for (int jj = 0; jj < 8; jj++)
    Wg[(size_t)(j0 + jj) * D_ + d] = acc[jj];
}

// ---------------------------------------------------------------------------
// counting sort of edges by src: histogram -> 3-phase scan -> scatter
// ---------------------------------------------------------------------------
__global__ __launch_bounds__(256) void hist_kernel(
    const int* __restrict__ src, int* __restrict__ hist) {
  const int e = blockIdx.x * 256 + threadIdx.x;
  if (e < E_) atomicAdd(&hist[src[e]], 1);
}

__global__ __launch_bounds__(256) void scan_phase1(
    const int* __restrict__ hist, int* __restrict__ csum) {
  __shared__ int s[256];
  s[threadIdx.x] = hist[blockIdx.x * 256 + threadIdx.x];
  __syncthreads();
#pragma unroll
  for (int d = 128; d >= 1; d >>= 1) {
    if (threadIdx.x < d) s[threadIdx.x] += s[threadIdx.x + d];
    __syncthreads();
  }
  if (threadIdx.x == 0) csum[blockIdx.x] = s[0];
}

__global__ void scan_phase2(const int* __restrict__ csum,
                            int* __restrict__ coff) {
  if (threadIdx.x == 0) {
    int acc = 0;
    for (int k = 0; k < 64; k++) { coff[k] = acc; acc += csum[k]; }
  }
}

__global__ __launch_bounds__(256) void scan_phase3(
    int* __restrict__ hist, const int* __restrict__ coff) {
  __shared__ int s[256];
  const int i = blockIdx.x * 256 + threadIdx.x;
  const int v = hist[i];
  s[threadIdx.x] = v;
  __syncthreads();
  for (int d = 1; d < 256; d <<= 1) {
    const int t = (threadIdx.x >= d) ? s[threadIdx.x - d] : 0;
    __syncthreads();
    s[threadIdx.x] += t;
    __syncthreads();
  }
  hist[i] = coff[blockIdx.x] + s[threadIdx.x] - v;  // exclusive prefix
}

__global__ __launch_bounds__(256) void scatter_kernel(
    const int* __restrict__ edges, int* __restrict__ cursor,
    int4* __restrict__ sorted) {
  const int e = blockIdx.x * 256 + threadIdx.x;
  if (e < E_) {
    const int s = edges[e];
    const int t = edges[E_ + e];
    const int pos = atomicAdd(&cursor[s], 1);
    sorted[pos] = make_int4(s, t, e, 0);
  }
}

// ---------------------------------------------------------------------------
// kernel 2: lemma_preds over src-sorted edges. 8 lanes per edge ->
// 16 independent 16 B loads/lane. Consecutive edges share the src row
// (L1-resident after first touch); Wg (2 MB) is L2-resident per XCD.
// ---------------------------------------------------------------------------
__global__ __launch_bounds__(256) void lemma_sorted(
    const float* __restrict__ scope, const float* __restrict__ Wg,
    const int4* __restrict__ sorted, const float* __restrict__ bias,
    float* __restrict__ out) {
  const int lane = threadIdx.x & 63;
  const int grp  = lane >> 3;   // edge slot in wave (0..7)
  const int l    = lane & 7;    // lane in group
  const int gw   = (blockIdx.x * 256 + threadIdx.x) >> 6;
  const int i    = gw * 8 + grp;
  if (i >= E_) return;          // group-uniform (8-lane granularity)
  const int4 st = sorted[i];
  const float4* sp = reinterpret_cast<const float4*>(scope + (size_t)st.x * TD_);
  const float4* wp = reinterpret_cast<const float4*>(Wg + (size_t)st.y * D_);
  float acc = 0.f;
#pragma unroll
  for (int k = 0; k < 8; k++) {
    const float4 a = sp[l + k * 8];
    const float4 b = wp[l + k * 8];
    acc += a.x * b.x + a.y * b.y + a.z * b.z + a.w * b.w;
  }
  acc += __shfl_xor(acc, 1);
  acc += __shfl_xor(acc, 2);
  acc += __shfl_xor(acc, 4);
  if (l == 0) out[st.z] = acc + bias[0];
}

// ---------------------------------------------------------------------------
// kernel 3: lm_preds (unchanged from R2 — verified, ~15 µs)
// ---------------------------------------------------------------------------
__global__ __launch_bounds__(256) void lm_kernel(
    const float* __restrict__ scope, const int* __restrict__ lm_idx,
    const int* __restrict__ batch_pts, const void* __restrict__ tree_mask,
    const int* __restrict__ flag_p, float* __restrict__ out) {
  __shared__ float cand[32][260];
  __shared__ unsigned char tmask[32];
  __shared__ int mlist[M_];
  __shared__ int mcnt;
  const int b  = blockIdx.x >> 4;
  const int n0 = (blockIdx.x & 15) * 32;
  const int t  = threadIdx.x;

  if (t == 0) mcnt = 0;
  {
    const int lane = t & 63;
    const int r0   = t >> 6;
#pragma unroll
    for (int rr = 0; rr < 8; rr++) {
      const int row = rr * 4 + r0;
      const float4 v = *reinterpret_cast<const float4*>(
          scope + (size_t)(b * N_ + n0 + row) * TD_ + lane * 4);
      float* dst = &cand[row][lane * 4];
      dst[0] = v.x; dst[1] = v.y; dst[2] = v.z; dst[3] = v.w;
    }
  }
  const int flag = flag_p[0];
  if (t < 32) {
    const int n = b * N_ + n0 + t;
    int v;
    if (flag == 1)      v = ((const unsigned char*)tree_mask)[n] != 0;
    else if (flag == 2) v = ((const float*)tree_mask)[n] != 0.0f;
    else                v = ((const int*)tree_mask)[n] != 0;
    tmask[t] = (unsigned char)v;
  }
  __syncthreads();

#pragma unroll
  for (int c = 0; c < M_ / 256; c++) {
    const int m = c * 256 + t;
    if (batch_pts[m] == b) {
      const int p = atomicAdd(&mcnt, 1);
      mlist[p] = m;
    }
  }
  __syncthreads();
  const int cnt = mcnt;

  const int nl = t >> 3;
  const int kg = t & 7;
  for (int k = 0; k < cnt; k++) {
    const int m = mlist[k];
    const float4* q =
        reinterpret_cast<const float4*>(scope + (size_t)lm_idx[m] * D_);
    float acc = 0.f;
#pragma unroll
    for (int i = 0; i < 8; i++) {
      const int f4 = kg * 8 + i;
      const float4 qv = q[f4];
      const float* cp = &cand[nl][f4 * 4];
      acc += qv.x * cp[0] + qv.y * cp[1] + qv.z * cp[2] + qv.w * cp[3];
    }
    acc += __shfl_xor(acc, 1);
    acc += __shfl_xor(acc, 2);
    acc += __shfl_xor(acc, 4);
    if (kg == 0)
      out[(size_t)m * N_ + (n0 + nl)] = tmask[nl] ? acc : NEG_;
  }
}

// ---------------------------------------------------------------------------
extern "C" void kernel_launch(void* const* d_in, const int* in_sizes, int n_in,
                              void* d_out, int out_size, void* d_ws,
                              size_t ws_size, hipStream_t stream) {
  const float* scope = (const float*)d_in[0];
  const float* goal  = (const float*)d_in[1];
  const float* W     = (const float*)d_in[2];
  const float* bias  = (const float*)d_in[3];
  const int*   edges = (const int*)d_in[4];
  const int*   lmidx = (const int*)d_in[5];
  const int*   bpts  = (const int*)d_in[6];
  const void*  tmask = d_in[7];

  float* out    = (float*)d_out;
  char*  ws     = (char*)d_ws;
  float* Wg     = (float*)(ws + WS_WG);
  float* Wt     = (float*)(ws + WS_WT);
  int*   flag   = (int*)(ws + WS_FLAG);
  int*   hist   = (int*)(ws + WS_HIST);
  int*   csum   = (int*)(ws + WS_CSUM);
  int*   coff   = (int*)(ws + WS_COFF);
  int4*  sorted = (int4*)(ws + WS_SORTED);

  detect_and_zero<<<1, 256, 0, stream>>>((const unsigned char*)tmask, flag,
                                         hist);
  transpose_w<<<64, 256, 0, stream>>>(W, Wt);
  wg_gemm<<<256, 256, 0, stream>>>(goal, Wt, Wg);
  hist_kernel<<<(E_ + 255) / 256, 256, 0, stream>>>(edges, hist);
  scan_phase1<<<S_ / 256, 256, 0, stream>>>(hist, csum);
  scan_phase2<<<1, 64, 0, stream>>>(csum, coff);
  scan_phase3<<<S_ / 256, 256, 0, stream>>>(hist, coff);
  scatter_kernel<<<(E_ + 255) / 256, 256, 0, stream>>>(edges, hist, sorted);
  lemma_sorted<<<(E_ + 31) / 32, 256, 0, stream>>>(scope, Wg, sorted, bias,
                                                   out);
  lm_kernel<<<B_ * 16, 256, 0, stream>>>(scope, lmidx, bpts, tmask, flag,
                                         out + E_);
}

// Round 4
// 483.652 us; speedup vs baseline: 1.1221x; 1.1221x over previous
//
#include <hip/hip_runtime.h>

#define B_   32
#define N_   512
#define G_   64
#define T_   16
#define D_   256
#define E_   500000
#define M_   1024
#define S_   (B_ * N_)          // 16384 distinct source rows
#define TT_  2048               // B_*G_ distinct target rows
#define TD_  (T_ * D_)          // 4096 floats between scope_type rows
#define NEG_ (-10000000000.0f)

// ws layout (bytes)
#define WS_WT    0              // 256 KiB  (W transposed, fp32)
#define WS_WGB   262144         // 1 MiB    (Wg bf16, 2048x256)
#define WS_SCB   2097152        // 8 MiB    (scope_type bf16, 16384x256)
#define WS_FLAG  10485760       // 4 B
#define WS_P     16777216       // 134 MiB  (P fp32, 16384x2048)

typedef short  short8 __attribute__((ext_vector_type(8)));
typedef float  f32x4  __attribute__((ext_vector_type(4)));

__device__ __forceinline__ unsigned short f2bf(float x) {
  union { float f; unsigned int u; } v; v.f = x;
  const unsigned int r = (v.u + 0x7fffu + ((v.u >> 16) & 1u)) >> 16;
  return (unsigned short)r;
}

// ---------------------------------------------------------------------------
// kernel 0: classify tree_mask storage. flag = 1 (bool), 2 (f32), 0 (i32).
// ---------------------------------------------------------------------------
__global__ __launch_bounds__(256) void detect_mask_dtype(
    const unsigned char* __restrict__ tm, int* __restrict__ flag) {
  __shared__ int sA, sB;
  if (threadIdx.x == 0) { sA = 0; sB = 0; }
  __syncthreads();
  int a = 0, b3 = 0;
  for (int i = threadIdx.x; i < B_ * N_; i += 256) {
    const int r = i & 3;
    const unsigned char v = tm[i];
    if (r == 1) a |= v;
    else if (r == 3) b3 |= v;
  }
  if (a)  atomicOr(&sA, 1);
  if (b3) atomicOr(&sB, 1);
  __syncthreads();
  if (threadIdx.x == 0) flag[0] = sA ? 1 : (sB ? 2 : 0);
}

// ---------------------------------------------------------------------------
// kernel 1a: Wt[f][d] = W[d][f]  (32x32 LDS tiles, +1 pad)
// ---------------------------------------------------------------------------
__global__ __launch_bounds__(256) void transpose_w(
    const float* __restrict__ W, float* __restrict__ Wt) {
  __shared__ float tile[32][33];
  const int bi = blockIdx.x >> 3;
  const int bj = blockIdx.x & 7;
  const int tx = threadIdx.x & 31;
  const int ty = threadIdx.x >> 5;
#pragma unroll
  for (int r = 0; r < 4; r++)
    tile[ty + r * 8][tx] = W[(size_t)(bi * 32 + ty + r * 8) * D_ + bj * 32 + tx];
  __syncthreads();
#pragma unroll
  for (int r = 0; r < 4; r++)
    Wt[(size_t)(bj * 32 + ty + r * 8) * D_ + bi * 32 + tx] =
        tile[tx][ty + r * 8];
}

// ---------------------------------------------------------------------------
// kernel 1b: Wg_bf16[j][d] = bf16( sum_f goal_type[j][f] * Wt[f][d] )
// fp32 math, bf16 store (feeds the MFMA GEMM).
// ---------------------------------------------------------------------------
__global__ __launch_bounds__(256) void wg_gemm(
    const float* __restrict__ goal, const float* __restrict__ Wt,
    unsigned short* __restrict__ Wgb) {
  __shared__ float g[8][256];
  const int j0 = blockIdx.x * 8;
  const int d  = threadIdx.x;
  {
    const int lane = threadIdx.x & 63;
    const int r0   = threadIdx.x >> 6;
#pragma unroll
    for (int rr = 0; rr < 2; rr++) {
      const int row = rr * 4 + r0;
      const float4 v = *reinterpret_cast<const float4*>(
          goal + (size_t)(j0 + row) * TD_ + lane * 4);
      float* dst = &g[row][lane * 4];
      dst[0] = v.x; dst[1] = v.y; dst[2] = v.z; dst[3] = v.w;
    }
  }
  __syncthreads();
  float acc[8];
#pragma unroll
  for (int jj = 0; jj < 8; jj++) acc[jj] = 0.f;
#pragma unroll 4
  for (int f = 0; f < D_; f++) {
    const float w = Wt[(size_t)f * D_ + d];
#pragma unroll
    for (int jj = 0; jj < 8; jj++) acc[jj] = fmaf(g[jj][f], w, acc[jj]);
  }
#pragma unroll
  for (int jj = 0; jj < 8; jj++)
    Wgb[(size_t)(j0 + jj) * D_ + d] = f2bf(acc[jj]);
}

// ---------------------------------------------------------------------------
// kernel 1c: Sc_bf16[s][d] = bf16(scope_token_reprs[s][0][d]), s in [0,16384)
// ---------------------------------------------------------------------------
__global__ __launch_bounds__(256) void cast_scope(
    const float* __restrict__ scope, unsigned short* __restrict__ scb) {
  const int q   = blockIdx.x * 256 + threadIdx.x;  // quad id, < 16384*64
  const int row = q >> 6;
  const int c4  = q & 63;
  const float4 v =
      *reinterpret_cast<const float4*>(scope + (size_t)row * TD_ + c4 * 4);
  ushort4 o;
  o.x = f2bf(v.x); o.y = f2bf(v.y); o.z = f2bf(v.z); o.w = f2bf(v.w);
  *reinterpret_cast<ushort4*>(&scb[(size_t)row * D_ + c4 * 4]) = o;
}

// ---------------------------------------------------------------------------
// kernel 2: P = Sc (16384x256) @ Wg^T (256x2048), bf16 MFMA, fp32 out.
// 128x128 block tile, 4 waves of 64x64, BK=64, LDS stride 80 bf16
// (160 B: 16 B-aligned b128 ops; bank-group pattern provably uniform).
// ---------------------------------------------------------------------------
#define BM 128
#define BN 128
#define BK 64
#define LDT 80

__global__ __launch_bounds__(256) void gemm_p(
    const unsigned short* __restrict__ scb,
    const unsigned short* __restrict__ wgb, float* __restrict__ P) {
  __shared__ unsigned short As[BM][LDT];  // 20 KB
  __shared__ unsigned short Bs[BN][LDT];  // 20 KB
  const int sB   = blockIdx.x >> 4;       // 0..127
  const int tB   = blockIdx.x & 15;       // 0..15
  const int tid  = threadIdx.x;
  const int lane = tid & 63;
  const int w    = tid >> 6;
  const int wr   = (w >> 1) * 64;         // wave row offset in tile
  const int wc   = (w & 1) * 64;          // wave col offset in tile
  const int lr   = lane & 15;
  const int lq   = lane >> 4;

  f32x4 acc[4][4];
#pragma unroll
  for (int mi = 0; mi < 4; mi++)
#pragma unroll
    for (int ni = 0; ni < 4; ni++)
      acc[mi][ni] = (f32x4){0.f, 0.f, 0.f, 0.f};

  const int r0 = tid >> 3;  // 0..31
  const int kg = tid & 7;   // 0..7

  for (int ks = 0; ks < D_ / BK; ks++) {
    __syncthreads();
#pragma unroll
    for (int rr = 0; rr < 4; rr++) {
      const int row = r0 + rr * 32;
      *reinterpret_cast<uint4*>(&As[row][kg * 8]) =
          *reinterpret_cast<const uint4*>(
              &scb[(size_t)(sB * BM + row) * D_ + ks * BK + kg * 8]);
      *reinterpret_cast<uint4*>(&Bs[row][kg * 8]) =
          *reinterpret_cast<const uint4*>(
              &wgb[(size_t)(tB * BN + row) * D_ + ks * BK + kg * 8]);
    }
    __syncthreads();
#pragma unroll
    for (int s16 = 0; s16 < 2; s16++) {  // two K=32 steps per stage
      const int koff = s16 * 32 + lq * 8;
      short8 aF[4], bF[4];
#pragma unroll
      for (int mi = 0; mi < 4; mi++)
        aF[mi] = *reinterpret_cast<const short8*>(&As[wr + mi * 16 + lr][koff]);
#pragma unroll
      for (int ni = 0; ni < 4; ni++)
        bF[ni] = *reinterpret_cast<const short8*>(&Bs[wc + ni * 16 + lr][koff]);
#pragma unroll
      for (int mi = 0; mi < 4; mi++)
#pragma unroll
        for (int ni = 0; ni < 4; ni++)
          acc[mi][ni] = __builtin_amdgcn_mfma_f32_16x16x32_bf16(
              aF[mi], bF[ni], acc[mi][ni], 0, 0, 0);
    }
  }

  // C/D layout: col = lane&15, row = (lane>>4)*4 + reg   [m89-verified]
#pragma unroll
  for (int mi = 0; mi < 4; mi++) {
#pragma unroll
    for (int ni = 0; ni < 4; ni++) {
      const int colg = tB * BN + wc + ni * 16 + lr;
#pragma unroll
      for (int r = 0; r < 4; r++) {
        const int rowg = sB * BM + wr + mi * 16 + lq * 4 + r;
        P[(size_t)rowg * TT_ + colg] = acc[mi][ni][r];
      }
    }
  }
}

// ---------------------------------------------------------------------------
// kernel 3: lemma_preds[e] = P[src_e][tgt_e] + bias   (4 B gather per edge)
// ---------------------------------------------------------------------------
__global__ __launch_bounds__(256) void gather_edges(
    const float* __restrict__ P, const int* __restrict__ edges,
    const float* __restrict__ bias, float* __restrict__ out) {
  const int e = blockIdx.x * 256 + threadIdx.x;
  if (e >= E_) return;
  const int s = edges[e];
  const int t = edges[E_ + e];
  out[e] = P[(size_t)s * TT_ + t] + bias[0];
}

// ---------------------------------------------------------------------------
// kernel 4: lm_preds (unchanged from R2 — verified)
// ---------------------------------------------------------------------------
__global__ __launch_bounds__(256) void lm_kernel(
    const float* __restrict__ scope, const int* __restrict__ lm_idx,
    const int* __restrict__ batch_pts, const void* __restrict__ tree_mask,
    const int* __restrict__ flag_p, float* __restrict__ out) {
  __shared__ float cand[32][260];
  __shared__ unsigned char tmask[32];
  __shared__ int mlist[M_];
  __shared__ int mcnt;
  const int b  = blockIdx.x >> 4;
  const int n0 = (blockIdx.x & 15) * 32;
  const int t  = threadIdx.x;

  if (t == 0) mcnt = 0;
  {
    const int lane = t & 63;
    const int r0   = t >> 6;
#pragma unroll
    for (int rr = 0; rr < 8; rr++) {
      const int row = rr * 4 + r0;
      const float4 v = *reinterpret_cast<const float4*>(
          scope + (size_t)(b * N_ + n0 + row) * TD_ + lane * 4);
      float* dst = &cand[row][lane * 4];
      dst[0] = v.x; dst[1] = v.y; dst[2] = v.z; dst[3] = v.w;
    }
  }
  const int flag = flag_p[0];
  if (t < 32) {
    const int n = b * N_ + n0 + t;
    int v;
    if (flag == 1)      v = ((const unsigned char*)tree_mask)[n] != 0;
    else if (flag == 2) v = ((const float*)tree_mask)[n] != 0.0f;
    else                v = ((const int*)tree_mask)[n] != 0;
    tmask[t] = (unsigned char)v;
  }
  __syncthreads();

#pragma unroll
  for (int c = 0; c < M_ / 256; c++) {
    const int m = c * 256 + t;
    if (batch_pts[m] == b) {
      const int p = atomicAdd(&mcnt, 1);
      mlist[p] = m;
    }
  }
  __syncthreads();
  const int cnt = mcnt;

  const int nl = t >> 3;
  const int kg = t & 7;
  for (int k = 0; k < cnt; k++) {
    const int m = mlist[k];
    const float4* q =
        reinterpret_cast<const float4*>(scope + (size_t)lm_idx[m] * D_);
    float acc = 0.f;
#pragma unroll
    for (int i = 0; i < 8; i++) {
      const int f4 = kg * 8 + i;
      const float4 qv = q[f4];
      const float* cp = &cand[nl][f4 * 4];
      acc += qv.x * cp[0] + qv.y * cp[1] + qv.z * cp[2] + qv.w * cp[3];
    }
    acc += __shfl_xor(acc, 1);
    acc += __shfl_xor(acc, 2);
    acc += __shfl_xor(acc, 4);
    if (kg == 0)
      out[(size_t)m * N_ + (n0 + nl)] = tmask[nl] ? acc : NEG_;
  }
}

// ---------------------------------------------------------------------------
extern "C" void kernel_launch(void* const* d_in, const int* in_sizes, int n_in,
                              void* d_out, int out_size, void* d_ws,
                              size_t ws_size, hipStream_t stream) {
  const float* scope = (const float*)d_in[0];
  const float* goal  = (const float*)d_in[1];
  const float* W     = (const float*)d_in[2];
  const float* bias  = (const float*)d_in[3];
  const int*   edges = (const int*)d_in[4];
  const int*   lmidx = (const int*)d_in[5];
  const int*   bpts  = (const int*)d_in[6];
  const void*  tmask = d_in[7];

  float* out = (float*)d_out;
  char*  ws  = (char*)d_ws;
  float*          Wt   = (float*)(ws + WS_WT);
  unsigned short* Wgb  = (unsigned short*)(ws + WS_WGB);
  unsigned short* scb  = (unsigned short*)(ws + WS_SCB);
  int*            flag = (int*)(ws + WS_FLAG);
  float*          P    = (float*)(ws + WS_P);

  detect_mask_dtype<<<1, 256, 0, stream>>>((const unsigned char*)tmask, flag);
  transpose_w<<<64, 256, 0, stream>>>(W, Wt);
  wg_gemm<<<TT_ / 8, 256, 0, stream>>>(goal, Wt, Wgb);
  cast_scope<<<(S_ * 64) / 256, 256, 0, stream>>>(scope, scb);
  gemm_p<<<(S_ / BM) * (TT_ / BN), 256, 0, stream>>>(scb, Wgb, P);
  gather_edges<<<(E_ + 255) / 256, 256, 0, stream>>>(P, edges, bias, out);
  lm_kernel<<<B_ * 16, 256, 0, stream>>>(scope, lmidx, bpts, tmask, flag,
                                         out + E_);
}